// Round 2
// baseline (100.848 us; speedup 1.0000x reference)
//
#include <hip/hip_runtime.h>
#include <hip/hip_bf16.h>
#include <stdint.h>

#define B_ROWS 2048
#define FEAT   2048
#define NK     128
#define ND     16
#define NCOL   2048   // NK*ND

#define BM 128
#define BN 128
#define BK 64

typedef __attribute__((ext_vector_type(4))) float f32x4;
typedef __attribute__((ext_vector_type(8))) short bf16x8;

__device__ __forceinline__ unsigned short f32_to_bf16(float f) {
    uint32_t x = __float_as_uint(f);
    uint32_t r = (x + 0x7fffu + ((x >> 16) & 1u)) >> 16;  // RNE
    return (unsigned short)r;
}

// ------------- Kernel 1: fused x-convert + W-transpose/convert -----------
// blocks [0,4096): x f32 -> bf16, 4 elems/thread
// blocks [4096,8192): W [k][n] f32 -> Wt [n][k] bf16 via 32x32 LDS tile
__global__ __launch_bounds__(256) void k_prep(const float* __restrict__ x,
                                              const float* __restrict__ W,
                                              unsigned short* __restrict__ x_bf,
                                              unsigned short* __restrict__ Wt) {
    __shared__ float tile[32][33];
    int bb = blockIdx.x;
    if (bb < 4096) {
        int i = bb * 256 + threadIdx.x;
        float4 v = ((const float4*)x)[i];
        ushort4 o;
        o.x = f32_to_bf16(v.x); o.y = f32_to_bf16(v.y);
        o.z = f32_to_bf16(v.z); o.w = f32_to_bf16(v.w);
        ((ushort4*)x_bf)[i] = o;
    } else {
        bb -= 4096;
        int tid = threadIdx.x;
        int tx = tid & 31, ty = tid >> 5;   // 32 x 8
        int n0 = (bb & 63) * 32, k0 = (bb >> 6) * 32;
        #pragma unroll
        for (int i = 0; i < 4; ++i)
            tile[ty + i * 8][tx] = W[(size_t)(k0 + ty + i * 8) * NCOL + n0 + tx];
        __syncthreads();
        #pragma unroll
        for (int i = 0; i < 4; ++i)
            Wt[(size_t)(n0 + ty + i * 8) * FEAT + k0 + tx] = f32_to_bf16(tile[tx][ty + i * 8]);
    }
}

// ---------------- Kernel 2: bf16 MFMA GEMM, split-K over grid.z -----------
// A row-major [M][K] bf16, Bt row-major [N][K] bf16.
// Slice z computes K range [z*kt_per*BK, (z+1)*kt_per*BK) into Cpart + z*M*N.
__global__ __launch_bounds__(256) void k_gemm(const unsigned short* __restrict__ A,
                                              const unsigned short* __restrict__ Bt,
                                              float* __restrict__ Cparts,
                                              int kt_per) {
    __shared__ __align__(16) unsigned short As[BM * BK];  // [m][k] 16KB
    __shared__ __align__(16) unsigned short Bs[BN * BK];  // [n][k] 16KB
    const int tid  = threadIdx.x;
    const int wave = tid >> 6;
    const int lane = tid & 63;
    const int bm = blockIdx.y, bn = blockIdx.x, z = blockIdx.z;
    float* C = Cparts + (size_t)z * B_ROWS * NCOL;
    const int wm = (wave >> 1) * 64;
    const int wn = (wave & 1) * 64;

    const int srow  = lane >> 3;        // 0..7: row within 8-row staging chunk
    const int skcol = (lane & 7) * 8;   // k offset (8 bf16 = 16B per lane)

    f32x4 acc[4][4];
    #pragma unroll
    for (int i = 0; i < 4; ++i)
        #pragma unroll
        for (int j = 0; j < 4; ++j)
            acc[i][j] = (f32x4){0.f, 0.f, 0.f, 0.f};

    const int fr = lane & 15;
    const int fk = (lane >> 4) * 8;

    const int kt0 = z * kt_per;
    for (int kt = kt0; kt < kt0 + kt_per; ++kt) {
        const int k0 = kt * BK;
        __syncthreads();
        #pragma unroll
        for (int r = 0; r < 4; ++r) {
            const int mrow = wave * 32 + r * 8 + srow;
            const unsigned short* ga = A  + (size_t)(bm * BM + mrow) * FEAT + k0 + skcol;
            const unsigned short* gb = Bt + (size_t)(bn * BN + mrow) * FEAT + k0 + skcol;
            unsigned short* la = As + (wave * 4 + r) * 512;
            unsigned short* lb = Bs + (wave * 4 + r) * 512;
            __builtin_amdgcn_global_load_lds((const __attribute__((address_space(1))) uint32_t*)ga,
                                             (__attribute__((address_space(3))) uint32_t*)la, 16, 0, 0);
            __builtin_amdgcn_global_load_lds((const __attribute__((address_space(1))) uint32_t*)gb,
                                             (__attribute__((address_space(3))) uint32_t*)lb, 16, 0, 0);
        }
        __syncthreads();
        #pragma unroll
        for (int kk = 0; kk < BK; kk += 32) {
            bf16x8 av[4], bv[4];
            #pragma unroll
            for (int t = 0; t < 4; ++t)
                av[t] = *(const bf16x8*)&As[(wm + t * 16 + fr) * BK + kk + fk];
            #pragma unroll
            for (int t = 0; t < 4; ++t)
                bv[t] = *(const bf16x8*)&Bs[(wn + t * 16 + fr) * BK + kk + fk];
            #pragma unroll
            for (int i = 0; i < 4; ++i)
                #pragma unroll
                for (int j = 0; j < 4; ++j)
                    acc[i][j] = __builtin_amdgcn_mfma_f32_16x16x32_bf16(av[i], bv[j], acc[i][j], 0, 0, 0);
        }
    }

    // D layout: col = lane&15, row = (lane>>4)*4 + r  [m89/m91-verified]
    const int crow0 = bm * BM + wm + (lane >> 4) * 4;
    const int ccol0 = bn * BN + wn + (lane & 15);
    #pragma unroll
    for (int i = 0; i < 4; ++i)
        #pragma unroll
        for (int j = 0; j < 4; ++j)
            #pragma unroll
            for (int r = 0; r < 4; ++r)
                C[(size_t)(crow0 + i * 16 + r) * NCOL + ccol0 + j * 16] = acc[i][j][r];
}

// ---------------- Kernel 3: pairwise L1 + exp, TI=4 register tile ---------
// 128 threads = 4 batch rows x 32 threads; each thread owns 4 output kernels.
#define TI  4
#define RPB 4
__global__ __launch_bounds__(128) void k_pairwise(const float* __restrict__ p0,
                                                  const float* __restrict__ p1,
                                                  int nparts,
                                                  float* __restrict__ Os) {
    __shared__ float rows[RPB][NCOL];  // 32KB
    const int b0 = blockIdx.x * RPB;
    const int t = threadIdx.x;
    const int r  = t >> 5;     // 0..3: batch row within block
    const int tl = t & 31;     // thread within row

    // Stage summed partials into LDS (coalesced float4)
    const float4* s0 = (const float4*)(p0 + (size_t)b0 * NCOL);
    const float4* s1 = (const float4*)(p1 + (size_t)b0 * NCOL);
    float4* dst = (float4*)&rows[0][0];
    const int n4 = RPB * NCOL / 4;  // 2048
    if (nparts == 2) {
        for (int i = t; i < n4; i += 128) {
            float4 a = s0[i], c = s1[i];
            a.x += c.x; a.y += c.y; a.z += c.z; a.w += c.w;
            dst[i] = a;
        }
    } else {
        for (int i = t; i < n4; i += 128) dst[i] = s0[i];
    }

    // Own fragments from global (L2-hot; avoids 32-way LDS conflict on
    // the 256B-stride own-row reads)
    float mi[TI][ND];
    #pragma unroll
    for (int ti = 0; ti < TI; ++ti) {
        size_t base = ((size_t)(b0 + r) * NK + tl * TI + ti) * ND;
        #pragma unroll
        for (int d = 0; d < ND; d += 4) {
            float4 a = *(const float4*)(p0 + base + d);
            if (nparts == 2) {
                float4 c = *(const float4*)(p1 + base + d);
                a.x += c.x; a.y += c.y; a.z += c.z; a.w += c.w;
            }
            mi[ti][d] = a.x; mi[ti][d+1] = a.y; mi[ti][d+2] = a.z; mi[ti][d+3] = a.w;
        }
    }
    __syncthreads();

    const float* row = rows[r];
    float acc[TI] = {0.f, 0.f, 0.f, 0.f};
    for (int j = 0; j < NK; ++j) {
        float vj[ND];
        #pragma unroll
        for (int d = 0; d < ND; d += 4)
            *(float4*)&vj[d] = *(const float4*)&row[j * ND + d];
        #pragma unroll
        for (int ti = 0; ti < TI; ++ti) {
            float nrm = 0.f;
            #pragma unroll
            for (int d = 0; d < ND; ++d)
                nrm += fabsf(mi[ti][d] - vj[d]);
            acc[ti] += __expf(-nrm);  // j==own gives exp(-0)=1 exactly
        }
    }
    float4 o = {acc[0], acc[1], acc[2], acc[3]};
    *(float4*)&Os[(size_t)(b0 + r) * NK + tl * TI] = o;
}

extern "C" void kernel_launch(void* const* d_in, const int* in_sizes, int n_in,
                              void* d_out, int out_size, void* d_ws, size_t ws_size,
                              hipStream_t stream) {
    const float* x = (const float*)d_in[0];
    const float* W = (const float*)d_in[1];
    float* Os = (float*)d_out;

    char* ws = (char*)d_ws;
    unsigned short* x_bf = (unsigned short*)ws;                                // 8MB
    unsigned short* Wt   = (unsigned short*)(ws + (size_t)8  * 1024 * 1024);   // 8MB
    float*          Mp   = (float*)        (ws + (size_t)16 * 1024 * 1024);    // 16MB x nsplit

    const size_t part_elems = (size_t)B_ROWS * NCOL;
    const int nsplit = (ws_size >= (size_t)48 * 1024 * 1024) ? 2 : 1;

    k_prep<<<8192, 256, 0, stream>>>(x, W, x_bf, Wt);

    dim3 gg(NCOL / BN, B_ROWS / BM, nsplit);  // 16 x 16 x nsplit
    k_gemm<<<gg, 256, 0, stream>>>(x_bf, Wt, Mp, (FEAT / BK) / nsplit);

    k_pairwise<<<B_ROWS / RPB, 128, 0, stream>>>(Mp, Mp + part_elems, nsplit, Os);
}

// Round 3
// 80.673 us; speedup vs baseline: 1.2501x; 1.2501x over previous
//
#include <hip/hip_runtime.h>
#include <hip/hip_bf16.h>
#include <stdint.h>

#define B_ROWS 2048
#define FEAT   2048
#define NK     128
#define ND     16
#define NCOL   2048   // NK*ND

#define BM 128
#define BN 128
#define BK 64

typedef __attribute__((ext_vector_type(4))) float f32x4;
typedef __attribute__((ext_vector_type(8))) short bf16x8;

__device__ __forceinline__ unsigned short f32_to_bf16(float f) {
    uint32_t x = __float_as_uint(f);
    uint32_t r = (x + 0x7fffu + ((x >> 16) & 1u)) >> 16;  // RNE
    return (unsigned short)r;
}

// ------------- Kernel 1: fused x-convert + W-transpose/convert -----------
__global__ __launch_bounds__(256) void k_prep(const float* __restrict__ x,
                                              const float* __restrict__ W,
                                              unsigned short* __restrict__ x_bf,
                                              unsigned short* __restrict__ Wt) {
    __shared__ float tile[32][33];
    int bb = blockIdx.x;
    if (bb < 4096) {
        int i = bb * 256 + threadIdx.x;
        float4 v = ((const float4*)x)[i];
        ushort4 o;
        o.x = f32_to_bf16(v.x); o.y = f32_to_bf16(v.y);
        o.z = f32_to_bf16(v.z); o.w = f32_to_bf16(v.w);
        ((ushort4*)x_bf)[i] = o;
    } else {
        bb -= 4096;
        int tid = threadIdx.x;
        int tx = tid & 31, ty = tid >> 5;   // 32 x 8
        int n0 = (bb & 63) * 32, k0 = (bb >> 6) * 32;
        #pragma unroll
        for (int i = 0; i < 4; ++i)
            tile[ty + i * 8][tx] = W[(size_t)(k0 + ty + i * 8) * NCOL + n0 + tx];
        __syncthreads();
        #pragma unroll
        for (int i = 0; i < 4; ++i)
            Wt[(size_t)(n0 + ty + i * 8) * FEAT + k0 + tx] = f32_to_bf16(tile[tx][ty + i * 8]);
    }
}

// ---------------- Kernel 2: bf16 MFMA GEMM, split-K over grid.z -----------
__global__ __launch_bounds__(256) void k_gemm(const unsigned short* __restrict__ A,
                                              const unsigned short* __restrict__ Bt,
                                              float* __restrict__ Cparts,
                                              int kt_per) {
    __shared__ __align__(16) unsigned short As[BM * BK];  // 16KB
    __shared__ __align__(16) unsigned short Bs[BN * BK];  // 16KB
    const int tid  = threadIdx.x;
    const int wave = tid >> 6;
    const int lane = tid & 63;
    const int bm = blockIdx.y, bn = blockIdx.x, z = blockIdx.z;
    float* C = Cparts + (size_t)z * B_ROWS * NCOL;
    const int wm = (wave >> 1) * 64;
    const int wn = (wave & 1) * 64;

    const int srow  = lane >> 3;
    const int skcol = (lane & 7) * 8;

    f32x4 acc[4][4];
    #pragma unroll
    for (int i = 0; i < 4; ++i)
        #pragma unroll
        for (int j = 0; j < 4; ++j)
            acc[i][j] = (f32x4){0.f, 0.f, 0.f, 0.f};

    const int fr = lane & 15;
    const int fk = (lane >> 4) * 8;

    const int kt0 = z * kt_per;
    for (int kt = kt0; kt < kt0 + kt_per; ++kt) {
        const int k0 = kt * BK;
        __syncthreads();
        #pragma unroll
        for (int r = 0; r < 4; ++r) {
            const int mrow = wave * 32 + r * 8 + srow;
            const unsigned short* ga = A  + (size_t)(bm * BM + mrow) * FEAT + k0 + skcol;
            const unsigned short* gb = Bt + (size_t)(bn * BN + mrow) * FEAT + k0 + skcol;
            unsigned short* la = As + (wave * 4 + r) * 512;
            unsigned short* lb = Bs + (wave * 4 + r) * 512;
            __builtin_amdgcn_global_load_lds((const __attribute__((address_space(1))) uint32_t*)ga,
                                             (__attribute__((address_space(3))) uint32_t*)la, 16, 0, 0);
            __builtin_amdgcn_global_load_lds((const __attribute__((address_space(1))) uint32_t*)gb,
                                             (__attribute__((address_space(3))) uint32_t*)lb, 16, 0, 0);
        }
        __syncthreads();
        #pragma unroll
        for (int kk = 0; kk < BK; kk += 32) {
            bf16x8 av[4], bv[4];
            #pragma unroll
            for (int t = 0; t < 4; ++t)
                av[t] = *(const bf16x8*)&As[(wm + t * 16 + fr) * BK + kk + fk];
            #pragma unroll
            for (int t = 0; t < 4; ++t)
                bv[t] = *(const bf16x8*)&Bs[(wn + t * 16 + fr) * BK + kk + fk];
            #pragma unroll
            for (int i = 0; i < 4; ++i)
                #pragma unroll
                for (int j = 0; j < 4; ++j)
                    acc[i][j] = __builtin_amdgcn_mfma_f32_16x16x32_bf16(av[i], bv[j], acc[i][j], 0, 0, 0);
        }
    }

    const int crow0 = bm * BM + wm + (lane >> 4) * 4;
    const int ccol0 = bn * BN + wn + (lane & 15);
    #pragma unroll
    for (int i = 0; i < 4; ++i)
        #pragma unroll
        for (int j = 0; j < 4; ++j)
            #pragma unroll
            for (int r = 0; r < 4; ++r)
                C[(size_t)(crow0 + i * 16 + r) * NCOL + ccol0 + j * 16] = acc[i][j][r];
}

// ---------------- Kernel 3: pairwise L1 + exp -----------------------------
// TI=1, RPB=2: 256 threads = 2 rows x 128 threads; thread owns one output.
// 1024 blocks x 4 waves = 4096 waves = 4/SIMD (latency hiding restored).
// ILP: explicit tree-sum for the 16-term L1 (fp reassoc the compiler can't
// do) + j-unroll x2 with independent accumulators.
#define RPB 2
__device__ __forceinline__ float l1_16(const float* mi, const float* vj) {
    float d[ND];
    #pragma unroll
    for (int k = 0; k < ND; ++k) d[k] = mi[k] - vj[k];
    float s[8];
    #pragma unroll
    for (int k = 0; k < 8; ++k) s[k] = fabsf(d[2 * k]) + fabsf(d[2 * k + 1]);
    float q0 = (s[0] + s[1]) + (s[2] + s[3]);
    float q1 = (s[4] + s[5]) + (s[6] + s[7]);
    return q0 + q1;
}

__global__ __launch_bounds__(256) void k_pairwise(const float* __restrict__ p0,
                                                  const float* __restrict__ p1,
                                                  int nparts,
                                                  float* __restrict__ Os) {
    __shared__ float rows[RPB * NCOL];  // 16KB
    const int b0 = blockIdx.x * RPB;
    const int t = threadIdx.x;
    const int r = t >> 7;      // row within block (wave-uniform)
    const int i = t & 127;     // kernel index owned by this thread

    const float4* s0 = (const float4*)(p0 + (size_t)b0 * NCOL);
    const float4* s1 = (const float4*)(p1 + (size_t)b0 * NCOL);
    float4* dst = (float4*)rows;
    const int n4 = RPB * NCOL / 4;  // 1024
    if (nparts == 2) {
        for (int idx = t; idx < n4; idx += 256) {
            float4 a = s0[idx], c = s1[idx];
            a.x += c.x; a.y += c.y; a.z += c.z; a.w += c.w;
            dst[idx] = a;
        }
    } else {
        for (int idx = t; idx < n4; idx += 256) dst[idx] = s0[idx];
    }
    __syncthreads();

    const float* row = rows + r * NCOL;
    float mi[ND];
    #pragma unroll
    for (int d = 0; d < ND; d += 4)
        *(float4*)&mi[d] = *(const float4*)&row[i * ND + d];

    float acc0 = 0.f, acc1 = 0.f;
    for (int j = 0; j < NK; j += 2) {
        float vj0[ND], vj1[ND];
        #pragma unroll
        for (int d = 0; d < ND; d += 4)
            *(float4*)&vj0[d] = *(const float4*)&row[j * ND + d];        // wave-uniform -> broadcast
        #pragma unroll
        for (int d = 0; d < ND; d += 4)
            *(float4*)&vj1[d] = *(const float4*)&row[(j + 1) * ND + d];
        acc0 += __expf(-l1_16(mi, vj0));   // j==i gives exp(-0)=1 exactly
        acc1 += __expf(-l1_16(mi, vj1));
    }
    Os[(size_t)(b0 + r) * NK + i] = acc0 + acc1;
}

extern "C" void kernel_launch(void* const* d_in, const int* in_sizes, int n_in,
                              void* d_out, int out_size, void* d_ws, size_t ws_size,
                              hipStream_t stream) {
    const float* x = (const float*)d_in[0];
    const float* W = (const float*)d_in[1];
    float* Os = (float*)d_out;

    char* ws = (char*)d_ws;
    unsigned short* x_bf = (unsigned short*)ws;                                // 8MB
    unsigned short* Wt   = (unsigned short*)(ws + (size_t)8  * 1024 * 1024);   // 8MB
    float*          Mp   = (float*)        (ws + (size_t)16 * 1024 * 1024);    // 16MB x nsplit

    const size_t part_elems = (size_t)B_ROWS * NCOL;
    const int nsplit = (ws_size >= (size_t)48 * 1024 * 1024) ? 2 : 1;

    k_prep<<<8192, 256, 0, stream>>>(x, W, x_bf, Wt);

    dim3 gg(NCOL / BN, B_ROWS / BM, nsplit);  // 16 x 16 x nsplit
    k_gemm<<<gg, 256, 0, stream>>>(x_bf, Wt, Mp, (FEAT / BK) / nsplit);

    k_pairwise<<<B_ROWS / RPB, 256, 0, stream>>>(Mp, Mp + part_elems, nsplit, Os);
}